// Round 11
// baseline (301.545 us; speedup 1.0000x reference)
//
#include <hip/hip_runtime.h>
#include <math.h>

static inline size_t align256(size_t x) { return (x + 255) & ~(size_t)255; }

typedef __attribute__((ext_vector_type(8))) short bf16x8;
typedef __attribute__((ext_vector_type(4))) float f32x4;
typedef __attribute__((ext_vector_type(2))) float f32x2;
typedef __attribute__((ext_vector_type(2))) _Float16 half2_t;

// ---- bf16 helpers (fp32 accumulate everywhere; bf16 is storage only) ----
__device__ inline float bfLo(unsigned int u) {
  union { unsigned int i; float f; } v; v.i = u << 16; return v.f;
}
__device__ inline float bfHi(unsigned int u) {
  union { unsigned int i; float f; } v; v.i = u & 0xffff0000u; return v.f;
}
__device__ inline unsigned short f2bf(float f) {
  union { float f; unsigned int i; } v; v.f = f;
  unsigned int r = v.i + 0x7FFF + ((v.i >> 16) & 1);  // RNE
  return (unsigned short)(r >> 16);
}
__device__ inline unsigned int packbf(float lo, float hi) {
  return ((unsigned int)f2bf(hi) << 16) | f2bf(lo);
}

// ---- fp8 e4m3 (OCP) helpers — HW converters on gfx950 ----
__device__ inline f32x2 f8lo(unsigned int u) {
  return __builtin_amdgcn_cvt_pk_f32_fp8(u, false);
}
__device__ inline f32x2 f8hi(unsigned int u) {
  return __builtin_amdgcn_cvt_pk_f32_fp8(u, true);
}
// encode one f32 -> e4m3 byte (RNE, saturating)
__device__ inline unsigned char f2f8(float f) {
  unsigned int v = (unsigned int)__builtin_amdgcn_cvt_pk_fp8_f32(f, f, 0, false);
  return (unsigned char)(v & 0xffu);
}
// pack 4 f32 -> 4 e4m3 bytes in one dword
__device__ inline unsigned int pack4f8(float a, float b, float c, float d) {
  unsigned int v = (unsigned int)__builtin_amdgcn_cvt_pk_fp8_f32(a, b, 0, false);
  v = (unsigned int)__builtin_amdgcn_cvt_pk_fp8_f32(c, d, (int)v, true);
  return v;
}

// ============ graph build: two-level LDS-privatized binning ============
// src-side degree via LDS histograms + keys array (global atomics measured 5x
// slower on CDNA4: non-coherent per-XCD L2s make them memory-side RMWs — R9).
// k_prep folded in: blocks also transpose W1/W2 to bf16 n-major.
__global__ __launch_bounds__(256) void k_coarse_count(const int* __restrict__ esrc,
                                                      const int* __restrict__ edst,
                                                      int E, int chunk, int NB, int G,
                                                      int* __restrict__ blkD,
                                                      int* __restrict__ blkS,
                                                      const float* __restrict__ W1,
                                                      const float* __restrict__ W2,
                                                      unsigned short* __restrict__ W1t,
                                                      unsigned short* __restrict__ W2t) {
  __shared__ int hD[512], hS[512];
  int blk = blockIdx.x, tid = threadIdx.x;
  int t = blk * 256 + tid;
  if (t < 128 * 128) {
    int nn = t >> 7, kk = t & 127;
    W1t[t] = f2bf(W1[kk * 128 + nn]);
  }
  if (t < 64 * 128) {
    int nn = t >> 7, kk = t & 127;
    W2t[t] = f2bf(W2[kk * 64 + nn]);
  }
  for (int i = tid; i < NB; i += 256) { hD[i] = 0; hS[i] = 0; }
  __syncthreads();
  int s0 = blk * chunk, s1 = min(E, s0 + chunk);
  for (int e = s0 + tid; e < s1; e += 256) {
    atomicAdd(&hD[edst[e] >> 8], 1);
    atomicAdd(&hS[esrc[e] >> 8], 1);
  }
  __syncthreads();
  for (int i = tid; i < NB; i += 256) {
    blkD[i * G + blk] = hD[i];
    blkS[i * G + blk] = hS[i];
  }
}

__global__ __launch_bounds__(256) void k_scan1(const int* __restrict__ in,
                                               int* __restrict__ out,
                                               int* __restrict__ bsums, int n) {
  __shared__ int s[256];
  int tid = threadIdx.x, gid = blockIdx.x * 256 + tid;
  int v = (gid < n) ? in[gid] : 0;
  s[tid] = v; __syncthreads();
  for (int o = 1; o < 256; o <<= 1) {
    int t = (tid >= o) ? s[tid - o] : 0;
    __syncthreads();
    s[tid] += t;
    __syncthreads();
  }
  if (gid < n) out[gid] = s[tid] - v;
  if (tid == 255) bsums[blockIdx.x] = s[255];
}

// grid = 2: block b scans bsums[b*nb .. b*nb+nb) independently (D half, S half)
__global__ __launch_bounds__(512) void k_scan2(int* __restrict__ bsums, int nb) {
  __shared__ int s[512];
  int tid = threadIdx.x;
  int* base = bsums + blockIdx.x * nb;
  int v = (tid < nb) ? base[tid] : 0;
  s[tid] = v; __syncthreads();
  for (int o = 1; o < 512; o <<= 1) {
    int t = (tid >= o) ? s[tid - o] : 0;
    __syncthreads();
    s[tid] += t;
    __syncthreads();
  }
  if (tid < nb) base[tid] = s[tid] - v;
}

// P3: packed scatter. pair = (src<<8)|(dst&255). scan3b folded: with G=256,
// full-scan value at sc[i*G+blk] = sc[i*G+blk] + bsums[i] (D) / bsums[NB+i] (S).
__global__ __launch_bounds__(256) void k_coarse_scatter(const int* __restrict__ esrc,
                                                        const int* __restrict__ edst,
                                                        int E, int chunk, int NB, int G,
                                                        const int* __restrict__ scD,
                                                        const int* __restrict__ scS,
                                                        const int* __restrict__ bsums,
                                                        unsigned int* __restrict__ pairs,
                                                        unsigned int* __restrict__ keys) {
  __shared__ int cD[512], cS[512];
  int blk = blockIdx.x, tid = threadIdx.x;
  for (int i = tid; i < NB; i += 256) {
    cD[i] = scD[i * G + blk] + bsums[i];
    cS[i] = scS[i * G + blk] + bsums[NB + i];
  }
  __syncthreads();
  int s0 = blk * chunk, s1 = min(E, s0 + chunk);
  for (int e = s0 + tid; e < s1; e += 256) {
    int s = esrc[e], d = edst[e];
    int pd = atomicAdd(&cD[d >> 8], 1);
    pairs[pd] = ((unsigned)s << 8) | ((unsigned)d & 255u);
    int ps = atomicAdd(&cS[s >> 8], 1);
    keys[ps] = (unsigned)s;
  }
}

// merged fine pass: blocks [0,NB) = dst buckets (csr build), [NB,2NB) = src buckets (normOut)
__global__ __launch_bounds__(256) void k_fine(const unsigned int* __restrict__ pairs,
                                              const unsigned int* __restrict__ keys,
                                              const int* __restrict__ scD,
                                              const int* __restrict__ scS,
                                              const int* __restrict__ bsums,
                                              int G, int E, int N, int NB,
                                              int* __restrict__ cntIn,
                                              float* __restrict__ normIn,
                                              int* __restrict__ offs,
                                              int* __restrict__ csr,
                                              float* __restrict__ normOut) {
  __shared__ int hist[256], scn[256], cur[256];
  int tid = threadIdx.x;
  if (blockIdx.x >= (unsigned)NB) {   // src half: degree -> normOut
    int b = blockIdx.x - NB;
    int bstart = scS[b * G] + bsums[NB + b];
    int bend = (b + 1 < NB) ? scS[(b + 1) * G] + bsums[NB + b + 1] : E;
    hist[tid] = 0;
    __syncthreads();
    for (int e = bstart + tid; e < bend; e += 256)
      atomicAdd(&hist[keys[e] & 255u], 1);
    __syncthreads();
    int node = b * 256 + tid;
    if (node < N) normOut[node] = rsqrtf((float)max(hist[tid], 1));
    return;
  }
  int b = blockIdx.x;
  int bstart = scD[b * G] + bsums[b];
  int bend = (b + 1 < NB) ? scD[(b + 1) * G] + bsums[b + 1] : E;
  hist[tid] = 0;
  __syncthreads();
  for (int e = bstart + tid; e < bend; e += 256)
    atomicAdd(&hist[pairs[e] & 255u], 1);
  __syncthreads();
  int v = hist[tid];
  scn[tid] = v;
  __syncthreads();
  for (int o = 1; o < 256; o <<= 1) {
    int t = (tid >= o) ? scn[tid - o] : 0;
    __syncthreads();
    scn[tid] += t;
    __syncthreads();
  }
  int excl = scn[tid] - v;
  cur[tid] = excl;
  int node = b * 256 + tid;
  if (node < N) {
    cntIn[node] = v;
    normIn[node] = rsqrtf((float)max(v, 1));
    offs[node] = bstart + excl;
  }
  __syncthreads();
  for (int e = bstart + tid; e < bend; e += 256) {
    unsigned int u = pairs[e];
    int p = bstart + atomicAdd(&cur[u & 255u], 1);
    csr[p] = (int)(u >> 8);
  }
}

// ---------------- MFMA GEMM: out[n x C] = diag(scale)*A[n x 128] @ W[128 x C] ----------------
// OF8: output stored as fp8 e4m3 (feeds a gather-bound aggregation); else bf16.
template <int C, typename TA, bool OF8>
__global__ __launch_bounds__(256) void k_mgemm(const TA* __restrict__ A,
                                               const float* __restrict__ scale,
                                               const unsigned short* __restrict__ Wt,
                                               unsigned short* __restrict__ out, int n) {
  constexpr int KP = 136;
  constexpr int NCH = C / 16;
  __shared__ __align__(16) unsigned short Al[64 * KP];
  __shared__ __align__(16) unsigned short Wl[C * KP];
  int tid = threadIdx.x;
  int r0 = blockIdx.x * 64;

  {
    const uint4* Wg = (const uint4*)Wt;
    uint4* Wd = (uint4*)Wl;
    for (int idx = tid; idx < C * 16; idx += 256) {
      int row = idx >> 4, seg = idx & 15;
      Wd[row * 17 + seg] = Wg[idx];
    }
  }
  {
    int seg = tid & 7;
    for (int it = 0; it < 2; ++it) {
      int row = (tid >> 3) + it * 32;
      int g = r0 + row;
      float v[16];
      if (g < n) {
        float sc = scale[g];
        if constexpr (sizeof(TA) == 4) {
          const float4* Ag = (const float4*)((const float*)A + (size_t)g * 128);
#pragma unroll
          for (int j = 0; j < 4; ++j) {
            float4 f = Ag[seg * 4 + j];
            v[j * 4 + 0] = f.x * sc; v[j * 4 + 1] = f.y * sc;
            v[j * 4 + 2] = f.z * sc; v[j * 4 + 3] = f.w * sc;
          }
        } else {
          const uint4* Ag = (const uint4*)((const unsigned short*)A + (size_t)g * 128);
#pragma unroll
          for (int j = 0; j < 2; ++j) {
            uint4 u = Ag[seg * 2 + j];
            v[j * 8 + 0] = bfLo(u.x) * sc; v[j * 8 + 1] = bfHi(u.x) * sc;
            v[j * 8 + 2] = bfLo(u.y) * sc; v[j * 8 + 3] = bfHi(u.y) * sc;
            v[j * 8 + 4] = bfLo(u.z) * sc; v[j * 8 + 5] = bfHi(u.z) * sc;
            v[j * 8 + 6] = bfLo(u.w) * sc; v[j * 8 + 7] = bfHi(u.w) * sc;
          }
        }
      } else {
#pragma unroll
        for (int j = 0; j < 16; ++j) v[j] = 0.f;
      }
      uint4* dst = (uint4*)(Al + row * KP + seg * 16);
      dst[0] = make_uint4(packbf(v[0], v[1]), packbf(v[2], v[3]),
                          packbf(v[4], v[5]), packbf(v[6], v[7]));
      dst[1] = make_uint4(packbf(v[8], v[9]), packbf(v[10], v[11]),
                          packbf(v[12], v[13]), packbf(v[14], v[15]));
    }
  }
  __syncthreads();

  int lane = tid & 63;
  int w = tid >> 6;
  int quad = lane >> 4, m16 = lane & 15;
  f32x4 acc[NCH];
#pragma unroll
  for (int c = 0; c < NCH; ++c) acc[c] = (f32x4){0.f, 0.f, 0.f, 0.f};

#pragma unroll
  for (int kc = 0; kc < 4; ++kc) {
    int ko = kc * 32 + quad * 8;
    bf16x8 a = *(const bf16x8*)(Al + (w * 16 + m16) * KP + ko);
#pragma unroll
    for (int c = 0; c < NCH; ++c) {
      bf16x8 b = *(const bf16x8*)(Wl + (c * 16 + m16) * KP + ko);
      acc[c] = __builtin_amdgcn_mfma_f32_16x16x32_bf16(a, b, acc[c], 0, 0, 0);
    }
  }

  if constexpr (OF8) {
    unsigned char* o8 = (unsigned char*)out;
#pragma unroll
    for (int c = 0; c < NCH; ++c)
#pragma unroll
      for (int r = 0; r < 4; ++r) {
        int g = r0 + w * 16 + quad * 4 + r;
        if (g < n) o8[(size_t)g * C + c * 16 + m16] = f2f8(acc[c][r]);
      }
  } else {
#pragma unroll
    for (int c = 0; c < NCH; ++c)
#pragma unroll
      for (int r = 0; r < 4; ++r) {
        int g = r0 + w * 16 + quad * 4 + r;
        if (g < n) out[(size_t)g * C + c * 16 + m16] = f2bf(acc[c][r]);
      }
  }
}

// ---------------- layer-1 aggregation over fp8 X1: fused-epoch batches ----------------
// 16 lanes x 8B (dwordx2) per edge, 4 edges concurrent. Remainders in (16,32] are
// handled by ONE fused 8-load epoch (4 unmasked + 4 masked loads all in flight)
// instead of two serial 4-deep epochs — the typical degree-17..31 node now pays one
// latency exposure. rem==16: pure unmasked batch; rem<16: masked 4-batch (as R10).
__global__ __launch_bounds__(256) void k_agg128f8_relu(const unsigned char* __restrict__ X,
                                                       const int* __restrict__ csr,
                                                       const int* __restrict__ offs,
                                                       const int* __restrict__ cnt,
                                                       const float* __restrict__ norm,
                                                       const float* __restrict__ bias,
                                                       unsigned short* __restrict__ H, int n) {
  int wid = blockIdx.x * 4 + (threadIdx.x >> 6);
  if (wid >= n) return;
  int lane = threadIdx.x & 63;
  int sub = lane & 15;          // 8B segment (8 cols) within the 128B row
  int grp = lane >> 4;          // 4 edges concurrent
  int start = offs[wid], m = cnt[wid];
  const int* p = csr + start;
  const uint2* Xv = (const uint2*)X;  // row stride 16 uint2
  f32x2 a0 = {0.f, 0.f}, a1 = {0.f, 0.f}, a2 = {0.f, 0.f}, a3 = {0.f, 0.f};
  for (int c0 = 0; c0 < m; c0 += 64) {
    int take = min(64, m - c0);
    int iv = p[c0 + ((lane < take) ? lane : take - 1)];   // one coalesced load
    int e = 0;
    for (; e + 32 <= take; e += 32) {    // rare (P(deg>=32) tiny at mean 16)
      uint2 uu[8];
#pragma unroll
      for (int j = 0; j < 8; ++j) {
        int ss = __shfl(iv, e + j * 4 + grp);
        uu[j] = Xv[(size_t)ss * 16 + sub];
      }
#pragma unroll
      for (int j = 0; j < 8; ++j) {
        a0 += f8lo(uu[j].x); a1 += f8hi(uu[j].x);
        a2 += f8lo(uu[j].y); a3 += f8hi(uu[j].y);
      }
    }
    int rem = take - e;
    if (rem > 16) {
      // fused epoch: 8 loads in flight (4 unmasked + 4 masked)
      uint2 uu[4], vv[4];
      int vm[4];
#pragma unroll
      for (int j = 0; j < 4; ++j) {
        int ss = __shfl(iv, e + j * 4 + grp);
        uu[j] = Xv[(size_t)ss * 16 + sub];
      }
#pragma unroll
      for (int j = 0; j < 4; ++j) {
        int idx = e + 16 + j * 4 + grp;
        vm[j] = (idx < take);
        int ss = __shfl(iv, vm[j] ? idx : take - 1);
        vv[j] = Xv[(size_t)ss * 16 + sub];
      }
#pragma unroll
      for (int j = 0; j < 4; ++j) {
        a0 += f8lo(uu[j].x); a1 += f8hi(uu[j].x);
        a2 += f8lo(uu[j].y); a3 += f8hi(uu[j].y);
      }
#pragma unroll
      for (int j = 0; j < 4; ++j) {
        unsigned ux = vm[j] ? vv[j].x : 0u;
        unsigned uy = vm[j] ? vv[j].y : 0u;
        a0 += f8lo(ux); a1 += f8hi(ux);
        a2 += f8lo(uy); a3 += f8hi(uy);
      }
    } else if (rem == 16) {
      uint2 uu[4];
#pragma unroll
      for (int j = 0; j < 4; ++j) {
        int ss = __shfl(iv, e + j * 4 + grp);
        uu[j] = Xv[(size_t)ss * 16 + sub];
      }
#pragma unroll
      for (int j = 0; j < 4; ++j) {
        a0 += f8lo(uu[j].x); a1 += f8hi(uu[j].x);
        a2 += f8lo(uu[j].y); a3 += f8hi(uu[j].y);
      }
    } else if (rem > 0) {
      uint2 uu[4];
      int vm[4];
#pragma unroll
      for (int j = 0; j < 4; ++j) {
        int idx = e + j * 4 + grp;
        vm[j] = (idx < take);
        int ss = __shfl(iv, vm[j] ? idx : take - 1);
        uu[j] = Xv[(size_t)ss * 16 + sub];
      }
#pragma unroll
      for (int j = 0; j < 4; ++j) {
        unsigned ux = vm[j] ? uu[j].x : 0u;
        unsigned uy = vm[j] ? uu[j].y : 0u;
        a0 += f8lo(ux); a1 += f8hi(ux);
        a2 += f8lo(uy); a3 += f8hi(uy);
      }
    }
  }
  float a[8] = {a0.x, a0.y, a1.x, a1.y, a2.x, a2.y, a3.x, a3.y};
#pragma unroll
  for (int k = 0; k < 8; ++k) {
    a[k] += __shfl_xor(a[k], 16);
    a[k] += __shfl_xor(a[k], 32);
  }
  float nm = norm[wid];
  const float4* bv = (const float4*)bias;     // cols sub*8 .. sub*8+7
  float4 b0 = bv[sub * 2], b1 = bv[sub * 2 + 1];
  if (grp == 0) {
    float o0 = fmaxf(a[0] * nm + b0.x, 0.f);
    float o1 = fmaxf(a[1] * nm + b0.y, 0.f);
    float o2 = fmaxf(a[2] * nm + b0.z, 0.f);
    float o3 = fmaxf(a[3] * nm + b0.w, 0.f);
    float o4 = fmaxf(a[4] * nm + b1.x, 0.f);
    float o5 = fmaxf(a[5] * nm + b1.y, 0.f);
    float o6 = fmaxf(a[6] * nm + b1.z, 0.f);
    float o7 = fmaxf(a[7] * nm + b1.w, 0.f);
    uint4 o = make_uint4(packbf(o0, o1), packbf(o2, o3),
                         packbf(o4, o5), packbf(o6, o7));
    ((uint4*)H)[(size_t)wid * 16 + sub] = o;
  }
}

// ---------------- layer-2 aggregation over fp8 X2b: fused-epoch batches ----------------
// X2b rows are 64B (64 x e4m3): 16 lanes x 4B (dword) per edge, 4 edges concurrent.
// Same fused-epoch structure as agg128f8. OUTPUT H2 fp8 (64B rows).
__global__ __launch_bounds__(256) void k_agg64f8(const unsigned char* __restrict__ X,
                                                 const int* __restrict__ csr,
                                                 const int* __restrict__ offs,
                                                 const int* __restrict__ cnt,
                                                 const float* __restrict__ norm,
                                                 const float* __restrict__ bias,
                                                 unsigned char* __restrict__ H, int n) {
  int wid = blockIdx.x * 4 + (threadIdx.x >> 6);
  if (wid >= n) return;
  int lane = threadIdx.x & 63;
  int sub = lane & 15;          // dword (4 cols) within the 64B row
  int grp = lane >> 4;          // 4 edges concurrent
  int start = offs[wid], m = cnt[wid];
  const int* p = csr + start;
  const unsigned* Xv = (const unsigned*)X;  // row stride 16 dwords
  f32x2 a0 = {0.f, 0.f}, a1 = {0.f, 0.f};
  for (int c0 = 0; c0 < m; c0 += 64) {
    int take = min(64, m - c0);
    int iv = p[c0 + ((lane < take) ? lane : take - 1)];
    int e = 0;
    for (; e + 32 <= take; e += 32) {    // rare
      unsigned uu[8];
#pragma unroll
      for (int j = 0; j < 8; ++j) {
        int ss = __shfl(iv, e + j * 4 + grp);
        uu[j] = Xv[(size_t)ss * 16 + sub];
      }
#pragma unroll
      for (int j = 0; j < 8; ++j) {
        a0 += f8lo(uu[j]); a1 += f8hi(uu[j]);
      }
    }
    int rem = take - e;
    if (rem > 16) {
      unsigned uu[4], vv[4];
      int vm[4];
#pragma unroll
      for (int j = 0; j < 4; ++j) {
        int ss = __shfl(iv, e + j * 4 + grp);
        uu[j] = Xv[(size_t)ss * 16 + sub];
      }
#pragma unroll
      for (int j = 0; j < 4; ++j) {
        int idx = e + 16 + j * 4 + grp;
        vm[j] = (idx < take);
        int ss = __shfl(iv, vm[j] ? idx : take - 1);
        vv[j] = Xv[(size_t)ss * 16 + sub];
      }
#pragma unroll
      for (int j = 0; j < 4; ++j) {
        a0 += f8lo(uu[j]); a1 += f8hi(uu[j]);
      }
#pragma unroll
      for (int j = 0; j < 4; ++j) {
        unsigned u = vm[j] ? vv[j] : 0u;
        a0 += f8lo(u); a1 += f8hi(u);
      }
    } else if (rem == 16) {
      unsigned uu[4];
#pragma unroll
      for (int j = 0; j < 4; ++j) {
        int ss = __shfl(iv, e + j * 4 + grp);
        uu[j] = Xv[(size_t)ss * 16 + sub];
      }
#pragma unroll
      for (int j = 0; j < 4; ++j) {
        a0 += f8lo(uu[j]); a1 += f8hi(uu[j]);
      }
    } else if (rem > 0) {
      unsigned uu[4];
      int vm[4];
#pragma unroll
      for (int j = 0; j < 4; ++j) {
        int idx = e + j * 4 + grp;
        vm[j] = (idx < take);
        int ss = __shfl(iv, vm[j] ? idx : take - 1);
        uu[j] = Xv[(size_t)ss * 16 + sub];
      }
#pragma unroll
      for (int j = 0; j < 4; ++j) {
        unsigned u = vm[j] ? uu[j] : 0u;
        a0 += f8lo(u); a1 += f8hi(u);
      }
    }
  }
  float a[4] = {a0.x, a0.y, a1.x, a1.y};
#pragma unroll
  for (int k = 0; k < 4; ++k) {
    a[k] += __shfl_xor(a[k], 16);
    a[k] += __shfl_xor(a[k], 32);
  }
  if (grp == 0) {
    float nm = norm[wid];
    const float4* bv = (const float4*)bias;   // cols sub*4 .. sub*4+3
    float4 b0 = bv[sub];
    unsigned w0 = pack4f8(a[0] * nm + b0.x, a[1] * nm + b0.y,
                          a[2] * nm + b0.z, a[3] * nm + b0.w);
    ((unsigned*)H)[(size_t)wid * 16 + sub] = w0;   // 64B row = 16 dwords
  }
}

// ---------------- edge scoring: 8 lanes/query, FOUR queries/thread, fp8 rows ----------------
__global__ __launch_bounds__(256) void k_score(const unsigned char* __restrict__ H,
                                               const int* __restrict__ qs,
                                               const int* __restrict__ qd,
                                               float* __restrict__ out, int q, int qStride) {
  int t = blockIdx.x * 256 + threadIdx.x;
  int sub = t & 7;
  int q0 = t >> 3;
  const uint2* Hv = (const uint2*)H;   // row stride 8 uint2 (64B fp8)
  int qi[4];
  bool has[4];
  uint2 A[4], B[4];
#pragma unroll
  for (int i = 0; i < 4; ++i) {
    qi[i] = q0 + i * qStride;
    has[i] = (qi[i] < q);
  }
#pragma unroll
  for (int i = 0; i < 4; ++i) {
    if (has[i]) {
      A[i] = Hv[(size_t)qs[qi[i]] * 8 + sub];
      B[i] = Hv[(size_t)qd[qi[i]] * 8 + sub];
    }
  }
  float p[4] = {0.f, 0.f, 0.f, 0.f};
#pragma unroll
  for (int i = 0; i < 4; ++i) {
    if (has[i]) {
      f32x2 acc = f8lo(A[i].x) * f8lo(B[i].x);
      acc += f8hi(A[i].x) * f8hi(B[i].x);
      acc += f8lo(A[i].y) * f8lo(B[i].y);
      acc += f8hi(A[i].y) * f8hi(B[i].y);
      p[i] = acc.x + acc.y;
    }
  }
#pragma unroll
  for (int i = 0; i < 4; ++i) {
    p[i] += __shfl_xor(p[i], 1);
    p[i] += __shfl_xor(p[i], 2);
    p[i] += __shfl_xor(p[i], 4);
  }
  if (sub == 0) {
#pragma unroll
    for (int i = 0; i < 4; ++i)
      if (has[i]) out[qi[i]] = 1.f / (1.f + expf(-p[i]));
  }
}

extern "C" void kernel_launch(void* const* d_in, const int* in_sizes, int n_in,
                              void* d_out, int out_size, void* d_ws, size_t ws_size,
                              hipStream_t stream) {
  const float* feat = (const float*)d_in[0];
  const int* esrc   = (const int*)d_in[1];
  const int* edst   = (const int*)d_in[2];
  const int* qsrc   = (const int*)d_in[3];
  const int* qdst   = (const int*)d_in[4];
  const float* W1   = (const float*)d_in[5];
  const float* b1   = (const float*)d_in[6];
  const float* W2   = (const float*)d_in[7];
  const float* b2   = (const float*)d_in[8];
  float* out = (float*)d_out;

  const int N = in_sizes[0] / 128;
  const int E = in_sizes[1];
  const int Q = in_sizes[3];

  const int G = 256;
  const int NB = (N + 255) >> 8;
  const int chunk = (E + G - 1) / G;
  const int lenS = NB * G;
  const int gScan = lenS / 256;        // == NB, blocks per half

  char* w = (char*)d_ws;
  size_t o = 0;
  // bufA: X1 fp8 (N x 128B); later reused for X2b fp8 (N x 64B) once X1 is consumed.
  unsigned char* bufA = (unsigned char*)(w + o); o += align256((size_t)N * 128);
  // bufH1: H1 bf16 (N x 256B)
  unsigned short* bufH1 = (unsigned short*)(w + o); o += align256((size_t)N * 128 * 2);
  // bufH2: H2 fp8 (N x 64B)
  unsigned char* bufH2 = (unsigned char*)(w + o); o += align256((size_t)N * 64);
  int* cntIn = (int*)(w + o);       o += align256((size_t)N * 4);
  float* normOut = (float*)(w + o); o += align256((size_t)N * 4);
  float* normIn = (float*)(w + o);  o += align256((size_t)N * 4);
  int* offs = (int*)(w + o);        o += align256((size_t)N * 4);
  int* blk = (int*)(w + o);         o += align256((size_t)lenS * 8);   // D half + S half
  int* sc = (int*)(w + o);          o += align256((size_t)lenS * 8);   // D half + S half
  int* bsums = (int*)(w + o);       o += align256((size_t)8192);
  unsigned short* W1t = (unsigned short*)(w + o); o += align256((size_t)128 * 128 * 2);
  unsigned short* W2t = (unsigned short*)(w + o); o += align256((size_t)64 * 128 * 2);
  unsigned int* pairs = (unsigned int*)(w + o); o += align256((size_t)E * 4);
  unsigned int* keys = (unsigned int*)(w + o); o += align256((size_t)E * 4);
  int* csr = (int*)(w + o);         o += align256((size_t)E * 4);

  int* blkD = blk;        int* blkS = blk + lenS;
  int* scD = sc;          int* scS = sc + lenS;

  // graph build (no global atomics); prep folded into count, scan3 folded into consumers
  k_coarse_count<<<G, 256, 0, stream>>>(esrc, edst, E, chunk, NB, G, blkD, blkS,
                                        W1, W2, W1t, W2t);
  k_scan1<<<2 * gScan, 256, 0, stream>>>(blk, sc, bsums, 2 * lenS);
  k_scan2<<<2, 512, 0, stream>>>(bsums, gScan);
  k_coarse_scatter<<<G, 256, 0, stream>>>(esrc, edst, E, chunk, NB, G, scD, scS,
                                          bsums, pairs, keys);
  k_fine<<<2 * NB, 256, 0, stream>>>(pairs, keys, scD, scS, bsums, G, E, N, NB,
                                     cntIn, normIn, offs, csr, normOut);

  const int gRows = (N + 63) / 64;
  // layer 1: X1(fp8) = (feat*normOut)@W1 ; H1(bf16) = relu(agg(X1)*normIn + b1)
  k_mgemm<128, float, true><<<gRows, 256, 0, stream>>>(feat, normOut, W1t,
                                                       (unsigned short*)bufA, N);
  k_agg128f8_relu<<<(N + 3) / 4, 256, 0, stream>>>(bufA, csr, offs, cntIn, normIn,
                                                   b1, bufH1, N);
  // layer 2: X2b(fp8) = (H1*normOut)@W2 ; H2(fp8) = agg(X2b)*normIn + b2
  // (bufA is free: X1 fully consumed by agg128f8)
  k_mgemm<64, unsigned short, true><<<gRows, 256, 0, stream>>>(bufH1, normOut, W2t,
                                                               (unsigned short*)bufA, N);
  k_agg64f8<<<(N + 3) / 4, 256, 0, stream>>>(bufA, csr, offs, cntIn, normIn, b2,
                                             bufH2, N);
  // scoring: 4 queries per thread, fp8 rows, 8 uint2 gathers in flight
  const int qQuarter = (Q + 3) / 4;
  k_score<<<((qQuarter * 8) + 255) / 256, 256, 0, stream>>>(bufH2, qsrc, qdst, out,
                                                            Q, qQuarter);
}

// Round 12
// 290.510 us; speedup vs baseline: 1.0380x; 1.0380x over previous
//
#include <hip/hip_runtime.h>
#include <math.h>

static inline size_t align256(size_t x) { return (x + 255) & ~(size_t)255; }

typedef __attribute__((ext_vector_type(8))) short bf16x8;
typedef __attribute__((ext_vector_type(4))) float f32x4;
typedef __attribute__((ext_vector_type(2))) float f32x2;
typedef __attribute__((ext_vector_type(2))) _Float16 half2_t;

// ---- bf16 helpers (fp32 accumulate everywhere; bf16 is storage only) ----
__device__ inline float bfLo(unsigned int u) {
  union { unsigned int i; float f; } v; v.i = u << 16; return v.f;
}
__device__ inline float bfHi(unsigned int u) {
  union { unsigned int i; float f; } v; v.i = u & 0xffff0000u; return v.f;
}
__device__ inline unsigned short f2bf(float f) {
  union { float f; unsigned int i; } v; v.f = f;
  unsigned int r = v.i + 0x7FFF + ((v.i >> 16) & 1);  // RNE
  return (unsigned short)(r >> 16);
}
__device__ inline unsigned int packbf(float lo, float hi) {
  return ((unsigned int)f2bf(hi) << 16) | f2bf(lo);
}

// ---- fp8 e4m3 (OCP) helpers — HW converters on gfx950 ----
__device__ inline f32x2 f8lo(unsigned int u) {
  return __builtin_amdgcn_cvt_pk_f32_fp8(u, false);
}
__device__ inline f32x2 f8hi(unsigned int u) {
  return __builtin_amdgcn_cvt_pk_f32_fp8(u, true);
}
// encode one f32 -> e4m3 byte (RNE, saturating)
__device__ inline unsigned char f2f8(float f) {
  unsigned int v = (unsigned int)__builtin_amdgcn_cvt_pk_fp8_f32(f, f, 0, false);
  return (unsigned char)(v & 0xffu);
}
// pack 4 f32 -> 4 e4m3 bytes in one dword
__device__ inline unsigned int pack4f8(float a, float b, float c, float d) {
  unsigned int v = (unsigned int)__builtin_amdgcn_cvt_pk_fp8_f32(a, b, 0, false);
  v = (unsigned int)__builtin_amdgcn_cvt_pk_fp8_f32(c, d, (int)v, true);
  return v;
}

// ============ graph build: two-level LDS-privatized binning ============
// src-side degree via LDS histograms + keys array (global atomics measured 5x
// slower on CDNA4: non-coherent per-XCD L2s make them memory-side RMWs — R9).
// k_prep folded in: blocks also transpose W1/W2 to bf16 n-major.
__global__ __launch_bounds__(256) void k_coarse_count(const int* __restrict__ esrc,
                                                      const int* __restrict__ edst,
                                                      int E, int chunk, int NB, int G,
                                                      int* __restrict__ blkD,
                                                      int* __restrict__ blkS,
                                                      const float* __restrict__ W1,
                                                      const float* __restrict__ W2,
                                                      unsigned short* __restrict__ W1t,
                                                      unsigned short* __restrict__ W2t) {
  __shared__ int hD[512], hS[512];
  int blk = blockIdx.x, tid = threadIdx.x;
  int t = blk * 256 + tid;
  if (t < 128 * 128) {
    int nn = t >> 7, kk = t & 127;
    W1t[t] = f2bf(W1[kk * 128 + nn]);
  }
  if (t < 64 * 128) {
    int nn = t >> 7, kk = t & 127;
    W2t[t] = f2bf(W2[kk * 64 + nn]);
  }
  for (int i = tid; i < NB; i += 256) { hD[i] = 0; hS[i] = 0; }
  __syncthreads();
  int s0 = blk * chunk, s1 = min(E, s0 + chunk);
  for (int e = s0 + tid; e < s1; e += 256) {
    atomicAdd(&hD[edst[e] >> 8], 1);
    atomicAdd(&hS[esrc[e] >> 8], 1);
  }
  __syncthreads();
  for (int i = tid; i < NB; i += 256) {
    blkD[i * G + blk] = hD[i];
    blkS[i * G + blk] = hS[i];
  }
}

__global__ __launch_bounds__(256) void k_scan1(const int* __restrict__ in,
                                               int* __restrict__ out,
                                               int* __restrict__ bsums, int n) {
  __shared__ int s[256];
  int tid = threadIdx.x, gid = blockIdx.x * 256 + tid;
  int v = (gid < n) ? in[gid] : 0;
  s[tid] = v; __syncthreads();
  for (int o = 1; o < 256; o <<= 1) {
    int t = (tid >= o) ? s[tid - o] : 0;
    __syncthreads();
    s[tid] += t;
    __syncthreads();
  }
  if (gid < n) out[gid] = s[tid] - v;
  if (tid == 255) bsums[blockIdx.x] = s[255];
}

// grid = 2: block b scans bsums[b*nb .. b*nb+nb) independently (D half, S half)
__global__ __launch_bounds__(512) void k_scan2(int* __restrict__ bsums, int nb) {
  __shared__ int s[512];
  int tid = threadIdx.x;
  int* base = bsums + blockIdx.x * nb;
  int v = (tid < nb) ? base[tid] : 0;
  s[tid] = v; __syncthreads();
  for (int o = 1; o < 512; o <<= 1) {
    int t = (tid >= o) ? s[tid - o] : 0;
    __syncthreads();
    s[tid] += t;
    __syncthreads();
  }
  if (tid < nb) base[tid] = s[tid] - v;
}

// P3: packed scatter. pair = (src<<8)|(dst&255). scan3b folded: with G=256,
// full-scan value at sc[i*G+blk] = sc[i*G+blk] + bsums[i] (D) / bsums[NB+i] (S).
__global__ __launch_bounds__(256) void k_coarse_scatter(const int* __restrict__ esrc,
                                                        const int* __restrict__ edst,
                                                        int E, int chunk, int NB, int G,
                                                        const int* __restrict__ scD,
                                                        const int* __restrict__ scS,
                                                        const int* __restrict__ bsums,
                                                        unsigned int* __restrict__ pairs,
                                                        unsigned int* __restrict__ keys) {
  __shared__ int cD[512], cS[512];
  int blk = blockIdx.x, tid = threadIdx.x;
  for (int i = tid; i < NB; i += 256) {
    cD[i] = scD[i * G + blk] + bsums[i];
    cS[i] = scS[i * G + blk] + bsums[NB + i];
  }
  __syncthreads();
  int s0 = blk * chunk, s1 = min(E, s0 + chunk);
  for (int e = s0 + tid; e < s1; e += 256) {
    int s = esrc[e], d = edst[e];
    int pd = atomicAdd(&cD[d >> 8], 1);
    pairs[pd] = ((unsigned)s << 8) | ((unsigned)d & 255u);
    int ps = atomicAdd(&cS[s >> 8], 1);
    keys[ps] = (unsigned)s;
  }
}

// merged fine pass: blocks [0,NB) = dst buckets (csr build), [NB,2NB) = src buckets (normOut)
__global__ __launch_bounds__(256) void k_fine(const unsigned int* __restrict__ pairs,
                                              const unsigned int* __restrict__ keys,
                                              const int* __restrict__ scD,
                                              const int* __restrict__ scS,
                                              const int* __restrict__ bsums,
                                              int G, int E, int N, int NB,
                                              int* __restrict__ cntIn,
                                              float* __restrict__ normIn,
                                              int* __restrict__ offs,
                                              int* __restrict__ csr,
                                              float* __restrict__ normOut) {
  __shared__ int hist[256], scn[256], cur[256];
  int tid = threadIdx.x;
  if (blockIdx.x >= (unsigned)NB) {   // src half: degree -> normOut
    int b = blockIdx.x - NB;
    int bstart = scS[b * G] + bsums[NB + b];
    int bend = (b + 1 < NB) ? scS[(b + 1) * G] + bsums[NB + b + 1] : E;
    hist[tid] = 0;
    __syncthreads();
    for (int e = bstart + tid; e < bend; e += 256)
      atomicAdd(&hist[keys[e] & 255u], 1);
    __syncthreads();
    int node = b * 256 + tid;
    if (node < N) normOut[node] = rsqrtf((float)max(hist[tid], 1));
    return;
  }
  int b = blockIdx.x;
  int bstart = scD[b * G] + bsums[b];
  int bend = (b + 1 < NB) ? scD[(b + 1) * G] + bsums[b + 1] : E;
  hist[tid] = 0;
  __syncthreads();
  for (int e = bstart + tid; e < bend; e += 256)
    atomicAdd(&hist[pairs[e] & 255u], 1);
  __syncthreads();
  int v = hist[tid];
  scn[tid] = v;
  __syncthreads();
  for (int o = 1; o < 256; o <<= 1) {
    int t = (tid >= o) ? scn[tid - o] : 0;
    __syncthreads();
    scn[tid] += t;
    __syncthreads();
  }
  int excl = scn[tid] - v;
  cur[tid] = excl;
  int node = b * 256 + tid;
  if (node < N) {
    cntIn[node] = v;
    normIn[node] = rsqrtf((float)max(v, 1));
    offs[node] = bstart + excl;
  }
  __syncthreads();
  for (int e = bstart + tid; e < bend; e += 256) {
    unsigned int u = pairs[e];
    int p = bstart + atomicAdd(&cur[u & 255u], 1);
    csr[p] = (int)(u >> 8);
  }
}

// ---------------- MFMA GEMM: out[n x C] = diag(scale)*A[n x 128] @ W[128 x C] ----------------
// OF8: output stored as fp8 e4m3 (feeds a gather-bound aggregation); else bf16.
template <int C, typename TA, bool OF8>
__global__ __launch_bounds__(256) void k_mgemm(const TA* __restrict__ A,
                                               const float* __restrict__ scale,
                                               const unsigned short* __restrict__ Wt,
                                               unsigned short* __restrict__ out, int n) {
  constexpr int KP = 136;
  constexpr int NCH = C / 16;
  __shared__ __align__(16) unsigned short Al[64 * KP];
  __shared__ __align__(16) unsigned short Wl[C * KP];
  int tid = threadIdx.x;
  int r0 = blockIdx.x * 64;

  {
    const uint4* Wg = (const uint4*)Wt;
    uint4* Wd = (uint4*)Wl;
    for (int idx = tid; idx < C * 16; idx += 256) {
      int row = idx >> 4, seg = idx & 15;
      Wd[row * 17 + seg] = Wg[idx];
    }
  }
  {
    int seg = tid & 7;
    for (int it = 0; it < 2; ++it) {
      int row = (tid >> 3) + it * 32;
      int g = r0 + row;
      float v[16];
      if (g < n) {
        float sc = scale[g];
        if constexpr (sizeof(TA) == 4) {
          const float4* Ag = (const float4*)((const float*)A + (size_t)g * 128);
#pragma unroll
          for (int j = 0; j < 4; ++j) {
            float4 f = Ag[seg * 4 + j];
            v[j * 4 + 0] = f.x * sc; v[j * 4 + 1] = f.y * sc;
            v[j * 4 + 2] = f.z * sc; v[j * 4 + 3] = f.w * sc;
          }
        } else {
          const uint4* Ag = (const uint4*)((const unsigned short*)A + (size_t)g * 128);
#pragma unroll
          for (int j = 0; j < 2; ++j) {
            uint4 u = Ag[seg * 2 + j];
            v[j * 8 + 0] = bfLo(u.x) * sc; v[j * 8 + 1] = bfHi(u.x) * sc;
            v[j * 8 + 2] = bfLo(u.y) * sc; v[j * 8 + 3] = bfHi(u.y) * sc;
            v[j * 8 + 4] = bfLo(u.z) * sc; v[j * 8 + 5] = bfHi(u.z) * sc;
            v[j * 8 + 6] = bfLo(u.w) * sc; v[j * 8 + 7] = bfHi(u.w) * sc;
          }
        }
      } else {
#pragma unroll
        for (int j = 0; j < 16; ++j) v[j] = 0.f;
      }
      uint4* dst = (uint4*)(Al + row * KP + seg * 16);
      dst[0] = make_uint4(packbf(v[0], v[1]), packbf(v[2], v[3]),
                          packbf(v[4], v[5]), packbf(v[6], v[7]));
      dst[1] = make_uint4(packbf(v[8], v[9]), packbf(v[10], v[11]),
                          packbf(v[12], v[13]), packbf(v[14], v[15]));
    }
  }
  __syncthreads();

  int lane = tid & 63;
  int w = tid >> 6;
  int quad = lane >> 4, m16 = lane & 15;
  f32x4 acc[NCH];
#pragma unroll
  for (int c = 0; c < NCH; ++c) acc[c] = (f32x4){0.f, 0.f, 0.f, 0.f};

#pragma unroll
  for (int kc = 0; kc < 4; ++kc) {
    int ko = kc * 32 + quad * 8;
    bf16x8 a = *(const bf16x8*)(Al + (w * 16 + m16) * KP + ko);
#pragma unroll
    for (int c = 0; c < NCH; ++c) {
      bf16x8 b = *(const bf16x8*)(Wl + (c * 16 + m16) * KP + ko);
      acc[c] = __builtin_amdgcn_mfma_f32_16x16x32_bf16(a, b, acc[c], 0, 0, 0);
    }
  }

  if constexpr (OF8) {
    unsigned char* o8 = (unsigned char*)out;
#pragma unroll
    for (int c = 0; c < NCH; ++c)
#pragma unroll
      for (int r = 0; r < 4; ++r) {
        int g = r0 + w * 16 + quad * 4 + r;
        if (g < n) o8[(size_t)g * C + c * 16 + m16] = f2f8(acc[c][r]);
      }
  } else {
#pragma unroll
    for (int c = 0; c < NCH; ++c)
#pragma unroll
      for (int r = 0; r < 4; ++r) {
        int g = r0 + w * 16 + quad * 4 + r;
        if (g < n) out[(size_t)g * C + c * 16 + m16] = f2bf(acc[c][r]);
      }
  }
}

// ---------------- layer-1 aggregation over fp8 X1: uniform 4-deep batches ----------------
// 16 lanes x 8B (dwordx2) per edge, 4 edges concurrent. Full 16-edge batches, then ONE
// masked 4-deep tail batch (wave-uniform branch): invalid slots clamp their shuffle to
// take-1 (same-line reload, ~free) and are zeroed before the fp8 convert.
// 32 VGPR / 8 waves/SIMD: latency hiding here is TLP — R11 proved trading occupancy
// for per-wave ILP (48 VGPR fused epochs) costs 20%.
__global__ __launch_bounds__(256) void k_agg128f8_relu(const unsigned char* __restrict__ X,
                                                       const int* __restrict__ csr,
                                                       const int* __restrict__ offs,
                                                       const int* __restrict__ cnt,
                                                       const float* __restrict__ norm,
                                                       const float* __restrict__ bias,
                                                       unsigned short* __restrict__ H, int n) {
  int wid = blockIdx.x * 4 + (threadIdx.x >> 6);
  if (wid >= n) return;
  int lane = threadIdx.x & 63;
  int sub = lane & 15;          // 8B segment (8 cols) within the 128B row
  int grp = lane >> 4;          // 4 edges concurrent
  int start = offs[wid], m = cnt[wid];
  const int* p = csr + start;
  const uint2* Xv = (const uint2*)X;  // row stride 16 uint2
  f32x2 a0 = {0.f, 0.f}, a1 = {0.f, 0.f}, a2 = {0.f, 0.f}, a3 = {0.f, 0.f};
  for (int c0 = 0; c0 < m; c0 += 64) {
    int take = min(64, m - c0);
    int iv = p[c0 + ((lane < take) ? lane : take - 1)];   // one coalesced load
    int full = take & ~15;
    int e = 0;
    for (; e < full; e += 16) {
      uint2 uu[4];
#pragma unroll
      for (int j = 0; j < 4; ++j) {
        int ss = __shfl(iv, e + j * 4 + grp);
        uu[j] = Xv[(size_t)ss * 16 + sub];
      }
#pragma unroll
      for (int j = 0; j < 4; ++j) {
        a0 += f8lo(uu[j].x); a1 += f8hi(uu[j].x);
        a2 += f8lo(uu[j].y); a3 += f8hi(uu[j].y);
      }
    }
    if (e < take) {   // masked 4-deep tail batch (take is wave-uniform)
      uint2 uu[4];
      int vm[4];
#pragma unroll
      for (int j = 0; j < 4; ++j) {
        int idx = e + j * 4 + grp;
        vm[j] = (idx < take);
        int ss = __shfl(iv, vm[j] ? idx : take - 1);
        uu[j] = Xv[(size_t)ss * 16 + sub];
      }
#pragma unroll
      for (int j = 0; j < 4; ++j) {
        unsigned ux = vm[j] ? uu[j].x : 0u;
        unsigned uy = vm[j] ? uu[j].y : 0u;
        a0 += f8lo(ux); a1 += f8hi(ux);
        a2 += f8lo(uy); a3 += f8hi(uy);
      }
    }
  }
  float a[8] = {a0.x, a0.y, a1.x, a1.y, a2.x, a2.y, a3.x, a3.y};
#pragma unroll
  for (int k = 0; k < 8; ++k) {
    a[k] += __shfl_xor(a[k], 16);
    a[k] += __shfl_xor(a[k], 32);
  }
  float nm = norm[wid];
  const float4* bv = (const float4*)bias;     // cols sub*8 .. sub*8+7
  float4 b0 = bv[sub * 2], b1 = bv[sub * 2 + 1];
  if (grp == 0) {
    float o0 = fmaxf(a[0] * nm + b0.x, 0.f);
    float o1 = fmaxf(a[1] * nm + b0.y, 0.f);
    float o2 = fmaxf(a[2] * nm + b0.z, 0.f);
    float o3 = fmaxf(a[3] * nm + b0.w, 0.f);
    float o4 = fmaxf(a[4] * nm + b1.x, 0.f);
    float o5 = fmaxf(a[5] * nm + b1.y, 0.f);
    float o6 = fmaxf(a[6] * nm + b1.z, 0.f);
    float o7 = fmaxf(a[7] * nm + b1.w, 0.f);
    uint4 o = make_uint4(packbf(o0, o1), packbf(o2, o3),
                         packbf(o4, o5), packbf(o6, o7));
    ((uint4*)H)[(size_t)wid * 16 + sub] = o;
  }
}

// ---------------- layer-2 aggregation over fp8 X2b: uniform 4-deep batches ----------------
// X2b rows are 64B (64 x e4m3): 16 lanes x 4B (dword) per edge, 4 edges concurrent.
// Same uniform batch + masked tail structure. OUTPUT H2 fp8 (64B rows).
__global__ __launch_bounds__(256) void k_agg64f8(const unsigned char* __restrict__ X,
                                                 const int* __restrict__ csr,
                                                 const int* __restrict__ offs,
                                                 const int* __restrict__ cnt,
                                                 const float* __restrict__ norm,
                                                 const float* __restrict__ bias,
                                                 unsigned char* __restrict__ H, int n) {
  int wid = blockIdx.x * 4 + (threadIdx.x >> 6);
  if (wid >= n) return;
  int lane = threadIdx.x & 63;
  int sub = lane & 15;          // dword (4 cols) within the 64B row
  int grp = lane >> 4;          // 4 edges concurrent
  int start = offs[wid], m = cnt[wid];
  const int* p = csr + start;
  const unsigned* Xv = (const unsigned*)X;  // row stride 16 dwords
  f32x2 a0 = {0.f, 0.f}, a1 = {0.f, 0.f};
  for (int c0 = 0; c0 < m; c0 += 64) {
    int take = min(64, m - c0);
    int iv = p[c0 + ((lane < take) ? lane : take - 1)];
    int full = take & ~15;
    int e = 0;
    for (; e < full; e += 16) {
      unsigned uu[4];
#pragma unroll
      for (int j = 0; j < 4; ++j) {
        int ss = __shfl(iv, e + j * 4 + grp);
        uu[j] = Xv[(size_t)ss * 16 + sub];
      }
#pragma unroll
      for (int j = 0; j < 4; ++j) {
        a0 += f8lo(uu[j]); a1 += f8hi(uu[j]);
      }
    }
    if (e < take) {   // masked 4-deep tail batch (take is wave-uniform)
      unsigned uu[4];
      int vm[4];
#pragma unroll
      for (int j = 0; j < 4; ++j) {
        int idx = e + j * 4 + grp;
        vm[j] = (idx < take);
        int ss = __shfl(iv, vm[j] ? idx : take - 1);
        uu[j] = Xv[(size_t)ss * 16 + sub];
      }
#pragma unroll
      for (int j = 0; j < 4; ++j) {
        unsigned u = vm[j] ? uu[j] : 0u;
        a0 += f8lo(u); a1 += f8hi(u);
      }
    }
  }
  float a[4] = {a0.x, a0.y, a1.x, a1.y};
#pragma unroll
  for (int k = 0; k < 4; ++k) {
    a[k] += __shfl_xor(a[k], 16);
    a[k] += __shfl_xor(a[k], 32);
  }
  if (grp == 0) {
    float nm = norm[wid];
    const float4* bv = (const float4*)bias;   // cols sub*4 .. sub*4+3
    float4 b0 = bv[sub];
    unsigned w0 = pack4f8(a[0] * nm + b0.x, a[1] * nm + b0.y,
                          a[2] * nm + b0.z, a[3] * nm + b0.w);
    ((unsigned*)H)[(size_t)wid * 16 + sub] = w0;   // 64B row = 16 dwords
  }
}

// ---------------- edge scoring: 8 lanes/query, FOUR queries/thread, fp8 rows ----------------
__global__ __launch_bounds__(256) void k_score(const unsigned char* __restrict__ H,
                                               const int* __restrict__ qs,
                                               const int* __restrict__ qd,
                                               float* __restrict__ out, int q, int qStride) {
  int t = blockIdx.x * 256 + threadIdx.x;
  int sub = t & 7;
  int q0 = t >> 3;
  const uint2* Hv = (const uint2*)H;   // row stride 8 uint2 (64B fp8)
  int qi[4];
  bool has[4];
  uint2 A[4], B[4];
#pragma unroll
  for (int i = 0; i < 4; ++i) {
    qi[i] = q0 + i * qStride;
    has[i] = (qi[i] < q);
  }
#pragma unroll
  for (int i = 0; i < 4; ++i) {
    if (has[i]) {
      A[i] = Hv[(size_t)qs[qi[i]] * 8 + sub];
      B[i] = Hv[(size_t)qd[qi[i]] * 8 + sub];
    }
  }
  float p[4] = {0.f, 0.f, 0.f, 0.f};
#pragma unroll
  for (int i = 0; i < 4; ++i) {
    if (has[i]) {
      f32x2 acc = f8lo(A[i].x) * f8lo(B[i].x);
      acc += f8hi(A[i].x) * f8hi(B[i].x);
      acc += f8lo(A[i].y) * f8lo(B[i].y);
      acc += f8hi(A[i].y) * f8hi(B[i].y);
      p[i] = acc.x + acc.y;
    }
  }
#pragma unroll
  for (int i = 0; i < 4; ++i) {
    p[i] += __shfl_xor(p[i], 1);
    p[i] += __shfl_xor(p[i], 2);
    p[i] += __shfl_xor(p[i], 4);
  }
  if (sub == 0) {
#pragma unroll
    for (int i = 0; i < 4; ++i)
      if (has[i]) out[qi[i]] = 1.f / (1.f + expf(-p[i]));
  }
}

extern "C" void kernel_launch(void* const* d_in, const int* in_sizes, int n_in,
                              void* d_out, int out_size, void* d_ws, size_t ws_size,
                              hipStream_t stream) {
  const float* feat = (const float*)d_in[0];
  const int* esrc   = (const int*)d_in[1];
  const int* edst   = (const int*)d_in[2];
  const int* qsrc   = (const int*)d_in[3];
  const int* qdst   = (const int*)d_in[4];
  const float* W1   = (const float*)d_in[5];
  const float* b1   = (const float*)d_in[6];
  const float* W2   = (const float*)d_in[7];
  const float* b2   = (const float*)d_in[8];
  float* out = (float*)d_out;

  const int N = in_sizes[0] / 128;
  const int E = in_sizes[1];
  const int Q = in_sizes[3];

  const int G = 256;
  const int NB = (N + 255) >> 8;
  const int chunk = (E + G - 1) / G;
  const int lenS = NB * G;
  const int gScan = lenS / 256;        // == NB, blocks per half

  char* w = (char*)d_ws;
  size_t o = 0;
  // bufA: X1 fp8 (N x 128B); later reused for X2b fp8 (N x 64B) once X1 is consumed.
  unsigned char* bufA = (unsigned char*)(w + o); o += align256((size_t)N * 128);
  // bufH1: H1 bf16 (N x 256B)
  unsigned short* bufH1 = (unsigned short*)(w + o); o += align256((size_t)N * 128 * 2);
  // bufH2: H2 fp8 (N x 64B)
  unsigned char* bufH2 = (unsigned char*)(w + o); o += align256((size_t)N * 64);
  int* cntIn = (int*)(w + o);       o += align256((size_t)N * 4);
  float* normOut = (float*)(w + o); o += align256((size_t)N * 4);
  float* normIn = (float*)(w + o);  o += align256((size_t)N * 4);
  int* offs = (int*)(w + o);        o += align256((size_t)N * 4);
  int* blk = (int*)(w + o);         o += align256((size_t)lenS * 8);   // D half + S half
  int* sc = (int*)(w + o);          o += align256((size_t)lenS * 8);   // D half + S half
  int* bsums = (int*)(w + o);       o += align256((size_t)8192);
  unsigned short* W1t = (unsigned short*)(w + o); o += align256((size_t)128 * 128 * 2);
  unsigned short* W2t = (unsigned short*)(w + o); o += align256((size_t)64 * 128 * 2);
  unsigned int* pairs = (unsigned int*)(w + o); o += align256((size_t)E * 4);
  unsigned int* keys = (unsigned int*)(w + o); o += align256((size_t)E * 4);
  int* csr = (int*)(w + o);         o += align256((size_t)E * 4);

  int* blkD = blk;        int* blkS = blk + lenS;
  int* scD = sc;          int* scS = sc + lenS;

  // graph build (no global atomics); prep folded into count, scan3 folded into consumers
  k_coarse_count<<<G, 256, 0, stream>>>(esrc, edst, E, chunk, NB, G, blkD, blkS,
                                        W1, W2, W1t, W2t);
  k_scan1<<<2 * gScan, 256, 0, stream>>>(blk, sc, bsums, 2 * lenS);
  k_scan2<<<2, 512, 0, stream>>>(bsums, gScan);
  k_coarse_scatter<<<G, 256, 0, stream>>>(esrc, edst, E, chunk, NB, G, scD, scS,
                                          bsums, pairs, keys);
  k_fine<<<2 * NB, 256, 0, stream>>>(pairs, keys, scD, scS, bsums, G, E, N, NB,
                                     cntIn, normIn, offs, csr, normOut);

  const int gRows = (N + 63) / 64;
  // layer 1: X1(fp8) = (feat*normOut)@W1 ; H1(bf16) = relu(agg(X1)*normIn + b1)
  k_mgemm<128, float, true><<<gRows, 256, 0, stream>>>(feat, normOut, W1t,
                                                       (unsigned short*)bufA, N);
  k_agg128f8_relu<<<(N + 3) / 4, 256, 0, stream>>>(bufA, csr, offs, cntIn, normIn,
                                                   b1, bufH1, N);
  // layer 2: X2b(fp8) = (H1*normOut)@W2 ; H2(fp8) = agg(X2b)*normIn + b2
  // (bufA is free: X1 fully consumed by agg128f8)
  k_mgemm<64, unsigned short, true><<<gRows, 256, 0, stream>>>(bufH1, normOut, W2t,
                                                               (unsigned short*)bufA, N);
  k_agg64f8<<<(N + 3) / 4, 256, 0, stream>>>(bufA, csr, offs, cntIn, normIn, b2,
                                             bufH2, N);
  // scoring: 4 queries per thread, fp8 rows, 8 uint2 gathers in flight
  const int qQuarter = (Q + 3) / 4;
  k_score<<<((qQuarter * 8) + 255) / 256, 256, 0, stream>>>(bufH2, qsrc, qdst, out,
                                                            Q, qQuarter);
}